// Round 2
// baseline (8826.285 us; speedup 1.0000x reference)
//
#include <hip/hip_runtime.h>

// Problem constants
#define T_STEPS 512
#define BATCH   256
#define DIN     128
#define DH      512
#define DOUT    128
#define GCOL    8          // colgroups per rowgroup
#define RGRP    16         // rowgroups (BATCH/16)

typedef __attribute__((ext_vector_type(8))) short  short8;   // 8 bf16 (4 VGPRs)
typedef __attribute__((ext_vector_type(4))) float  floatx4;  // MFMA acc

__device__ __forceinline__ float bf2f(unsigned short u) {
    union { unsigned int i; float f; } v; v.i = ((unsigned int)u) << 16; return v.f;
}
__device__ __forceinline__ unsigned short f2bf(float f) {
    union { float f; unsigned int i; } v; v.f = f;
    unsigned int b = v.i;
    b += 0x7FFFu + ((b >> 16) & 1u);   // RNE
    return (unsigned short)(b >> 16);
}
__device__ __forceinline__ float fast_tanh(float v) {
    float ex = __expf(v + v);
    return 1.f - 2.f / (ex + 1.f);
}

// ---------------------------------------------------------------------------
// Pack a row-major fp32 [K][N] matrix into bf16 B-fragment order:
//   Wp[ntile][kc][lane][8], lane = quad*16 + (n&15), element j = k&7.
// ---------------------------------------------------------------------------
__global__ void pack_b_kernel(const float* __restrict__ W,
                              unsigned short* __restrict__ Wp, int K, int N) {
    int idx = blockIdx.x * blockDim.x + threadIdx.x;
    if (idx >= K * N) return;
    int k = idx / N, n = idx % N;
    int nt = n >> 4, kc = k >> 5, quad = (k >> 3) & 3, j = k & 7;
    int lane = quad * 16 + (n & 15);
    int KC = K >> 5;
    Wp[((size_t)(nt * KC + kc) * 64 + lane) * 8 + j] = f2bf(W[idx]);
}

// ---------------------------------------------------------------------------
// xproj: xp[tb][n] = sum_k xs[tb][k] * W1x[k][n], stored bf16. (unchanged)
// ---------------------------------------------------------------------------
__global__ __launch_bounds__(256) void xproj_kernel(
        const float* __restrict__ xs,
        const unsigned short* __restrict__ W1xp,
        unsigned short* __restrict__ xp) {
    const int tid  = threadIdx.x;
    const int lane = tid & 63;
    const int w    = tid >> 6;       // 0..3
    const int m    = lane & 15;
    const int q    = lane >> 4;
    const long row0 = (long)blockIdx.x * 16;

    short8 a[4];
#pragma unroll
    for (int kc = 0; kc < 4; ++kc) {
        const float* src = xs + (row0 + m) * DIN + kc * 32 + q * 8;
        short8 av;
#pragma unroll
        for (int j = 0; j < 8; ++j) av[j] = (short)f2bf(src[j]);
        a[kc] = av;
    }

#pragma unroll
    for (int i = 0; i < 8; ++i) {
        const int nt = w * 8 + i;
        floatx4 acc = {0.f, 0.f, 0.f, 0.f};
#pragma unroll
        for (int kc = 0; kc < 4; ++kc) {
            short8 b = *(const short8*)(W1xp + ((size_t)(nt * 4 + kc) * 64 + lane) * 8);
            acc = __builtin_amdgcn_mfma_f32_16x16x32_bf16(a[kc], b, acc, 0, 0, 0);
        }
#pragma unroll
        for (int r = 0; r < 4; ++r) {
            long row = row0 + q * 4 + r;
            xp[row * DH + nt * 16 + m] = f2bf(acc[r]);
        }
    }
}

// ---------------------------------------------------------------------------
// Recurrence: 128 blocks (16 rowgroups x 8 colgroups) x 256 threads (4 waves).
// Block (rg,g): rows [16rg,16rg+16), cols [64g,64g+64). Wave w owns ntile
// ng=4g+w -> its 16-col W1h slice lives entirely in 64 VGPRs (zero steady-state
// B traffic). Per step: MFMA -> tanh -> write 2KB slice to hx (L3) -> agent
// release atomicAdd -> spin to 32 -> acquire fence -> stage 16KB h into LDS.
// The counter spin doubles as the block barrier for pre-spin LDS reads.
// ---------------------------------------------------------------------------
__global__ __launch_bounds__(256, 1) void rnn_kernel(
        const unsigned short* __restrict__ xp,
        const unsigned short* __restrict__ W1hp,
        const float* __restrict__ b1p,
        const float* __restrict__ W2,
        const float* __restrict__ b2p,
        float* __restrict__ out,
        unsigned short* __restrict__ hx,   // [2][RGRP][16][512] bf16
        unsigned int* __restrict__ cnt) {  // [T_STEPS][RGRP], zeroed per launch
    __shared__ unsigned short Hlds[16][520];   // +8 pad: balanced b128 banks

    const int tid  = threadIdx.x;
    const int lane = tid & 63;
    const int w    = tid >> 6;      // 0..3
    const int m    = lane & 15;
    const int q    = lane >> 4;
    const int g    = blockIdx.x & 7;
    const int rg   = blockIdx.x >> 3;
    const int ng   = g * 4 + w;     // this wave's ntile
    const int cb   = ng * 16;       // global h-column base
    const float b1 = b1p[0];

    // Preload this wave's W1h slice: 16 kc-fragments = 64 VGPRs
    short8 bfr[16];
#pragma unroll
    for (int kc = 0; kc < 16; ++kc)
        bfr[kc] = *(const short8*)(W1hp + ((size_t)(ng * 16 + kc) * 64 + lane) * 8);

    // h^1 = tanh(xp[0] + b1): computed locally (full 16x512), no exchange
#pragma unroll
    for (int p = 0; p < 4; ++p) {
        int c   = p * 256 + tid;          // 1024 chunks of 8 elems
        int row = c >> 6, cc = c & 63;
        const unsigned short* src = xp + (size_t)(rg * 16 + row) * DH + cc * 8;
        unsigned short tmp[8];
#pragma unroll
        for (int j = 0; j < 8; ++j) tmp[j] = f2bf(fast_tanh(bf2f(src[j]) + b1));
        *(short8*)&Hlds[row][cc * 8] = *(short8*)tmp;
    }
    __syncthreads();

#pragma unroll 1
    for (int i = 1; i < T_STEPS; ++i) {
        // xp prefetch for epilogue (static data, issue early)
        unsigned short xv[4];
#pragma unroll
        for (int r = 0; r < 4; ++r)
            xv[r] = xp[((size_t)i * BATCH + rg * 16 + q * 4 + r) * DH + cb + m];

        // A-fragments for all 16 k-chunks (frees LDS for post-spin staging)
        short8 a[16];
#pragma unroll
        for (int kc = 0; kc < 16; ++kc)
            a[kc] = *(const short8*)&Hlds[m][kc * 32 + q * 8];

        // Two independent 8-deep MFMA chains
        floatx4 acc0 = {0.f, 0.f, 0.f, 0.f}, acc1 = {0.f, 0.f, 0.f, 0.f};
#pragma unroll
        for (int kc = 0; kc < 8; ++kc) {
            acc0 = __builtin_amdgcn_mfma_f32_16x16x32_bf16(a[kc],     bfr[kc],     acc0, 0, 0, 0);
            acc1 = __builtin_amdgcn_mfma_f32_16x16x32_bf16(a[kc + 8], bfr[kc + 8], acc1, 0, 0, 0);
        }

        // Epilogue: own 16x16 tile of h^{i+1} -> exchange buffer
        const int slot = i & 1;
        unsigned short* hd = hx + ((size_t)(slot * RGRP + rg) * 16) * DH;
#pragma unroll
        for (int r = 0; r < 4; ++r) {
            float v = acc0[r] + acc1[r] + bf2f(xv[r]) + b1;
            hd[(size_t)(q * 4 + r) * DH + cb + m] = f2bf(fast_tanh(v));
        }

        // Release: one add per wave (target 32 = 8 blocks x 4 waves)
        unsigned int* c_i = cnt + i * RGRP + rg;
        if (lane == 0)
            __hip_atomic_fetch_add(c_i, 1u, __ATOMIC_RELEASE, __HIP_MEMORY_SCOPE_AGENT);

        // Spin until the whole rowgroup has published (also acts as block barrier)
        while (__hip_atomic_load(c_i, __ATOMIC_RELAXED, __HIP_MEMORY_SCOPE_AGENT) < 32u)
            __builtin_amdgcn_s_sleep(1);
        __builtin_amdgcn_fence(__ATOMIC_ACQUIRE, "agent");

        // Stage full h^{i+1} (16x512) into LDS
        const unsigned short* hs = hx + ((size_t)(slot * RGRP + rg) * 16) * DH;
#pragma unroll
        for (int p = 0; p < 4; ++p) {
            int c   = p * 256 + tid;
            int row = c >> 6, cc = c & 63;
            *(short8*)&Hlds[row][cc * 8] = *(const short8*)(hs + (size_t)row * DH + cc * 8);
        }
        __syncthreads();
    }

    // Tail: out[:, 16g:16g+16) = h^T @ W2 + b2 (wave 0 only; trivial work)
    if (w == 0) {
        const float b2 = b2p[0];
        floatx4 acc = {0.f, 0.f, 0.f, 0.f};
#pragma unroll
        for (int kc = 0; kc < 16; ++kc) {
            short8 av = *(const short8*)&Hlds[m][kc * 32 + q * 8];
            short8 bv;
#pragma unroll
            for (int j = 0; j < 8; ++j)
                bv[j] = (short)f2bf(W2[(size_t)(kc * 32 + q * 8 + j) * DOUT + g * 16 + m]);
            acc = __builtin_amdgcn_mfma_f32_16x16x32_bf16(av, bv, acc, 0, 0, 0);
        }
#pragma unroll
        for (int r = 0; r < 4; ++r)
            out[(size_t)(rg * 16 + q * 4 + r) * DOUT + g * 16 + m] = acc[r] + b2;
    }
}

// ---------------------------------------------------------------------------
extern "C" void kernel_launch(void* const* d_in, const int* in_sizes, int n_in,
                              void* d_out, int out_size, void* d_ws, size_t ws_size,
                              hipStream_t stream) {
    const float* xs  = (const float*)d_in[0];
    const float* W1x = (const float*)d_in[1];
    const float* W1h = (const float*)d_in[2];
    const float* b1  = (const float*)d_in[3];
    const float* W2  = (const float*)d_in[4];
    const float* b2  = (const float*)d_in[5];
    float* out = (float*)d_out;

    // Workspace layout (bf16 elems): xp | W1h packed | W1x packed | hx | cnt
    unsigned short* xp   = (unsigned short*)d_ws;
    unsigned short* w1hp = xp + (size_t)T_STEPS * BATCH * DH;      // 67,108,864
    unsigned short* w1xp = w1hp + (size_t)DH * DH;                 // +262,144
    unsigned short* hx   = w1xp + (size_t)DIN * DH;                // +65,536
    unsigned int*   cnt  = (unsigned int*)(hx + (size_t)2 * RGRP * 16 * DH);

    hipMemsetAsync(cnt, 0, (size_t)T_STEPS * RGRP * sizeof(unsigned int), stream);
    pack_b_kernel<<<(DH * DH + 255) / 256, 256, 0, stream>>>(W1h, w1hp, DH, DH);
    pack_b_kernel<<<(DIN * DH + 255) / 256, 256, 0, stream>>>(W1x, w1xp, DIN, DH);
    xproj_kernel<<<(T_STEPS * BATCH) / 16, 256, 0, stream>>>(xs, w1xp, xp);
    rnn_kernel<<<RGRP * GCOL, 256, 0, stream>>>(xp, w1hp, b1, W2, b2, out, hx, cnt);
}

// Round 3
// 4836.835 us; speedup vs baseline: 1.8248x; 1.8248x over previous
//
#include <hip/hip_runtime.h>

// Problem constants
#define T_STEPS 512
#define BATCH   256
#define DIN     128
#define DH      512
#define DOUT    128
#define HALF    256        // h-columns per block
#define RGRP    16         // rowgroups (BATCH/16)

typedef __attribute__((ext_vector_type(8))) short  short8;   // 8 bf16 (4 VGPRs)
typedef __attribute__((ext_vector_type(4))) float  floatx4;  // MFMA acc

union Pack8 { short8 s; unsigned long long u[2]; unsigned short h[8]; };

__device__ __forceinline__ float bf2f(unsigned short u) {
    union { unsigned int i; float f; } v; v.i = ((unsigned int)u) << 16; return v.f;
}
__device__ __forceinline__ unsigned short f2bf(float f) {
    union { float f; unsigned int i; } v; v.f = f;
    unsigned int b = v.i;
    b += 0x7FFFu + ((b >> 16) & 1u);   // RNE
    return (unsigned short)(b >> 16);
}
__device__ __forceinline__ float fast_tanh(float v) {
    float ex = __expf(v + v);
    return 1.f - 2.f / (ex + 1.f);
}

// hx: [2 slots][RGRP][2 halves][16 rows][HALF cols] bf16
#define HX(hx, slot, r, h) ((hx) + ((((size_t)(slot) * RGRP + (r)) * 2 + (h)) * 16) * HALF)

// ---------------------------------------------------------------------------
// Pack row-major fp32 [K][N] into bf16 B-fragment order:
//   Wp[ntile][kc][lane][8], lane = quad*16 + (n&15), j = k&7.
// ---------------------------------------------------------------------------
__global__ void pack_b_kernel(const float* __restrict__ W,
                              unsigned short* __restrict__ Wp, int K, int N) {
    int idx = blockIdx.x * blockDim.x + threadIdx.x;
    if (idx >= K * N) return;
    int k = idx / N, n = idx % N;
    int nt = n >> 4, kc = k >> 5, quad = (k >> 3) & 3, j = k & 7;
    int lane = quad * 16 + (n & 15);
    int KC = K >> 5;
    Wp[((size_t)(nt * KC + kc) * 64 + lane) * 8 + j] = f2bf(W[idx]);
}

// ---------------------------------------------------------------------------
// xproj: xp[tb][n] = sum_k xs[tb][k] * W1x[k][n], stored bf16.
// ---------------------------------------------------------------------------
__global__ __launch_bounds__(256) void xproj_kernel(
        const float* __restrict__ xs,
        const unsigned short* __restrict__ W1xp,
        unsigned short* __restrict__ xp) {
    const int tid  = threadIdx.x;
    const int lane = tid & 63;
    const int w    = tid >> 6;
    const int m    = lane & 15;
    const int q    = lane >> 4;
    const long row0 = (long)blockIdx.x * 16;

    short8 a[4];
#pragma unroll
    for (int kc = 0; kc < 4; ++kc) {
        const float* src = xs + (row0 + m) * DIN + kc * 32 + q * 8;
        Pack8 av;
#pragma unroll
        for (int j = 0; j < 8; ++j) av.h[j] = f2bf(src[j]);
        a[kc] = av.s;
    }

#pragma unroll
    for (int i = 0; i < 8; ++i) {
        const int nt = w * 8 + i;
        floatx4 acc = {0.f, 0.f, 0.f, 0.f};
#pragma unroll
        for (int kc = 0; kc < 4; ++kc) {
            short8 b = *(const short8*)(W1xp + ((size_t)(nt * 4 + kc) * 64 + lane) * 8);
            acc = __builtin_amdgcn_mfma_f32_16x16x32_bf16(a[kc], b, acc, 0, 0, 0);
        }
#pragma unroll
        for (int r = 0; r < 4; ++r)
            xp[(row0 + q * 4 + r) * DH + nt * 16 + m] = f2bf(acc[r]);
    }
}

// ---------------------------------------------------------------------------
// Recurrence: 32 blocks (16 rowgroups x 2 halves) x 512 threads (8 waves).
// Wave owns 2 ntiles -> its W1h slice = 32 frags = 128 VGPRs (fully resident).
// Per step: local-half MFMA -> spin partner flag (relaxed agent load) ->
// coherence-point load partner half -> partner MFMA -> tanh -> per-wave LDS
// transpose -> publish own half (relaxed agent stores + vmcnt(0) + relaxed
// atomicAdd). NO fences, NO release/acquire -> no wbl2 / L2 invalidation.
// ---------------------------------------------------------------------------
__global__ __launch_bounds__(512, 2) void rnn_kernel(
        const unsigned short* __restrict__ xp,
        const unsigned short* __restrict__ W1hp,
        const float* __restrict__ b1p,
        const float* __restrict__ W2,
        const float* __restrict__ b2p,
        float* __restrict__ out,
        unsigned short* __restrict__ hx,
        unsigned int* __restrict__ cnt) {  // [T_STEPS+1][RGRP][2], zeroed/launch
    __shared__ unsigned short Hlds[16][520];   // full h, +8 pad
    __shared__ unsigned short stg[8][16][32];  // per-wave transpose staging

    const int tid  = threadIdx.x;
    const int lane = tid & 63;
    const int w    = tid >> 6;      // 0..7
    const int m    = lane & 15;
    const int q    = lane >> 4;
    const int gid  = blockIdx.x;
    const int g    = (gid >> 3) & 1;                  // half; pair (id,id+8) likely same XCD
    const int rg   = (gid & 7) | ((gid >> 4) << 3);   // rowgroup 0..15
    const int pg   = 1 - g;
    const float b1 = b1p[0];
    const int ng0  = g * 16 + w * 2;                  // first of wave's 2 ntiles

    // W1h slice fully into VGPRs: 2 ntiles x 16 kc = 128 VGPRs
    short8 bfr[2][16];
#pragma unroll
    for (int t = 0; t < 2; ++t)
#pragma unroll
        for (int kc = 0; kc < 16; ++kc)
            bfr[t][kc] = *(const short8*)(W1hp + ((size_t)((ng0 + t) * 16 + kc) * 64 + lane) * 8);

    // ---- init: h^1 = tanh(xp[0] + b1), own half; publish to hx slot 1 ----
    {
        int row = tid >> 5, cc = tid & 31;
        const unsigned short* src = xp + (size_t)(rg * 16 + row) * DH + g * HALF + cc * 8;
        Pack8 pk;
#pragma unroll
        for (int j = 0; j < 8; ++j) pk.h[j] = f2bf(fast_tanh(bf2f(src[j]) + b1));
        unsigned long long* dst =
            (unsigned long long*)(HX(hx, 1, rg, g) + (size_t)row * HALF + cc * 8);
        __hip_atomic_store(dst,     pk.u[0], __ATOMIC_RELAXED, __HIP_MEMORY_SCOPE_AGENT);
        __hip_atomic_store(dst + 1, pk.u[1], __ATOMIC_RELAXED, __HIP_MEMORY_SCOPE_AGENT);
        *(short8*)&Hlds[row][g * HALF + cc * 8] = pk.s;
    }
    asm volatile("s_waitcnt vmcnt(0)" ::: "memory");
    if (lane == 0)
        __hip_atomic_fetch_add(cnt + ((size_t)1 * RGRP + rg) * 2 + g, 1u,
                               __ATOMIC_RELAXED, __HIP_MEMORY_SCOPE_AGENT);
    __syncthreads();

    short8 a_loc[8];
#pragma unroll
    for (int j = 0; j < 8; ++j)
        a_loc[j] = *(const short8*)&Hlds[m][(8 * g + j) * 32 + q * 8];

    // ---- main loop: iteration i consumes h^i, produces h^{i+1} ----
#pragma unroll 1
    for (int i = 1; i < T_STEPS; ++i) {
        const int slot_in  = i & 1;
        const int slot_out = slot_in ^ 1;

        // xp[i] prefetch (plain cached loads; caches never invalidated)
        unsigned short xv[2][4];
#pragma unroll
        for (int t = 0; t < 2; ++t)
#pragma unroll
            for (int r = 0; r < 4; ++r)
                xv[t][r] = xp[((size_t)i * BATCH + rg * 16 + q * 4 + r) * DH + (ng0 + t) * 16 + m];

        floatx4 acc0 = {0.f, 0.f, 0.f, 0.f}, acc1 = {0.f, 0.f, 0.f, 0.f};

        // local-half MFMA first (hides exchange RTT)
#pragma unroll
        for (int j = 0; j < 8; ++j) {
            int kc = 8 * g + j;
            acc0 = __builtin_amdgcn_mfma_f32_16x16x32_bf16(a_loc[j], bfr[0][kc], acc0, 0, 0, 0);
            acc1 = __builtin_amdgcn_mfma_f32_16x16x32_bf16(a_loc[j], bfr[1][kc], acc1, 0, 0, 0);
        }

        // spin for partner's h^i (relaxed agent load; no fence)
        {
            const unsigned int* flag = cnt + ((size_t)i * RGRP + rg) * 2 + pg;
            while (__hip_atomic_load(flag, __ATOMIC_RELAXED, __HIP_MEMORY_SCOPE_AGENT) < 8u)
                __builtin_amdgcn_s_sleep(1);
        }

        // coherence-point load of partner half -> LDS (wave's 1KB share)
        {
            int k = w * 128 + lane * 2;
            int row = k >> 6, c4 = (k & 63) * 4;
            const unsigned long long* srcp =
                (const unsigned long long*)(HX(hx, slot_in, rg, pg) + (size_t)row * HALF + c4);
            Pack8 pv;
            pv.u[0] = __hip_atomic_load(srcp,     __ATOMIC_RELAXED, __HIP_MEMORY_SCOPE_AGENT);
            pv.u[1] = __hip_atomic_load(srcp + 1, __ATOMIC_RELAXED, __HIP_MEMORY_SCOPE_AGENT);
            *(short8*)&Hlds[row][pg * HALF + c4] = pv.s;
        }
        __syncthreads();   // barrier 1: partner half staged

        // partner-half MFMA
#pragma unroll
        for (int j = 0; j < 8; ++j) {
            short8 ap = *(const short8*)&Hlds[m][(8 * pg + j) * 32 + q * 8];
            int kc = 8 * pg + j;
            acc0 = __builtin_amdgcn_mfma_f32_16x16x32_bf16(ap, bfr[0][kc], acc0, 0, 0, 0);
            acc1 = __builtin_amdgcn_mfma_f32_16x16x32_bf16(ap, bfr[1][kc], acc1, 0, 0, 0);
        }

        // epilogue: tanh -> per-wave transpose staging (wave-private, no barrier)
#pragma unroll
        for (int r = 0; r < 4; ++r) {
            stg[w][q * 4 + r][m]      = f2bf(fast_tanh(acc0[r] + bf2f(xv[0][r]) + b1));
            stg[w][q * 4 + r][16 + m] = f2bf(fast_tanh(acc1[r] + bf2f(xv[1][r]) + b1));
        }
        asm volatile("s_waitcnt lgkmcnt(0)" ::: "memory");
        Pack8 pk;
        pk.s = *(short8*)&stg[w][lane >> 2][(lane & 3) * 8];
        {
            int row = lane >> 2, c0 = w * 32 + (lane & 3) * 8;
            // publish own half (coherence-point stores)
            unsigned long long* dst =
                (unsigned long long*)(HX(hx, slot_out, rg, g) + (size_t)row * HALF + c0);
            __hip_atomic_store(dst,     pk.u[0], __ATOMIC_RELAXED, __HIP_MEMORY_SCOPE_AGENT);
            __hip_atomic_store(dst + 1, pk.u[1], __ATOMIC_RELAXED, __HIP_MEMORY_SCOPE_AGENT);
            // own half into LDS for next step
            *(short8*)&Hlds[row][g * HALF + c0] = pk.s;
        }
        asm volatile("s_waitcnt vmcnt(0)" ::: "memory");
        if (lane == 0)
            __hip_atomic_fetch_add(cnt + ((size_t)(i + 1) * RGRP + rg) * 2 + g, 1u,
                                   __ATOMIC_RELAXED, __HIP_MEMORY_SCOPE_AGENT);
        __syncthreads();   // barrier 2: h^{i+1} local staged

#pragma unroll
        for (int j = 0; j < 8; ++j)
            a_loc[j] = *(const short8*)&Hlds[m][(8 * g + j) * 32 + q * 8];
    }

    // ---- tail (g==0 blocks): fetch partner h^512, then out = h @ W2 + b2 ----
    if (g == 0) {
        const unsigned int* flag = cnt + ((size_t)T_STEPS * RGRP + rg) * 2 + 1;
        while (__hip_atomic_load(flag, __ATOMIC_RELAXED, __HIP_MEMORY_SCOPE_AGENT) < 8u)
            __builtin_amdgcn_s_sleep(1);
        {
            int k = w * 128 + lane * 2;
            int row = k >> 6, c4 = (k & 63) * 4;
            const unsigned long long* srcp =
                (const unsigned long long*)(HX(hx, 0, rg, 1) + (size_t)row * HALF + c4);
            Pack8 pv;
            pv.u[0] = __hip_atomic_load(srcp,     __ATOMIC_RELAXED, __HIP_MEMORY_SCOPE_AGENT);
            pv.u[1] = __hip_atomic_load(srcp + 1, __ATOMIC_RELAXED, __HIP_MEMORY_SCOPE_AGENT);
            *(short8*)&Hlds[row][HALF + c4] = pv.s;
        }
        __syncthreads();

        const float b2 = b2p[0];
        floatx4 acc = {0.f, 0.f, 0.f, 0.f};
#pragma unroll
        for (int kc = 0; kc < 16; ++kc) {
            short8 av = *(const short8*)&Hlds[m][kc * 32 + q * 8];
            Pack8 bv;
#pragma unroll
            for (int j = 0; j < 8; ++j)
                bv.h[j] = f2bf(W2[(size_t)(kc * 32 + q * 8 + j) * DOUT + w * 16 + m]);
            acc = __builtin_amdgcn_mfma_f32_16x16x32_bf16(av, bv.s, acc, 0, 0, 0);
        }
#pragma unroll
        for (int r = 0; r < 4; ++r)
            out[(size_t)(rg * 16 + q * 4 + r) * DOUT + w * 16 + m] = acc[r] + b2;
    }
}

// ---------------------------------------------------------------------------
extern "C" void kernel_launch(void* const* d_in, const int* in_sizes, int n_in,
                              void* d_out, int out_size, void* d_ws, size_t ws_size,
                              hipStream_t stream) {
    const float* xs  = (const float*)d_in[0];
    const float* W1x = (const float*)d_in[1];
    const float* W1h = (const float*)d_in[2];
    const float* b1  = (const float*)d_in[3];
    const float* W2  = (const float*)d_in[4];
    const float* b2  = (const float*)d_in[5];
    float* out = (float*)d_out;

    // ws (bf16 elems): xp | W1h packed | W1x packed | hx | cnt
    unsigned short* xp   = (unsigned short*)d_ws;
    unsigned short* w1hp = xp + (size_t)T_STEPS * BATCH * DH;      // 67,108,864
    unsigned short* w1xp = w1hp + (size_t)DH * DH;                 // +262,144
    unsigned short* hx   = w1xp + (size_t)DIN * DH;                // +65,536
    unsigned int*   cnt  = (unsigned int*)(hx + (size_t)2 * RGRP * 2 * 16 * HALF);

    hipMemsetAsync(cnt, 0, (size_t)(T_STEPS + 1) * RGRP * 2 * sizeof(unsigned int), stream);
    pack_b_kernel<<<(DH * DH + 255) / 256, 256, 0, stream>>>(W1h, w1hp, DH, DH);
    pack_b_kernel<<<(DIN * DH + 255) / 256, 256, 0, stream>>>(W1x, w1xp, DIN, DH);
    xproj_kernel<<<(T_STEPS * BATCH) / 16, 256, 0, stream>>>(xs, w1xp, xp);
    rnn_kernel<<<RGRP * 2, 512, 0, stream>>>(xp, w1hp, b1, W2, b2, out, hx, cnt);
}

// Round 5
// 1684.272 us; speedup vs baseline: 5.2404x; 2.8718x over previous
//
#include <hip/hip_runtime.h>

// Problem constants
#define T_STEPS 512
#define BATCH   256
#define DIN     128
#define DH      512
#define DOUT    128
#define RGRP    16         // rowgroups (BATCH/16), one block each

typedef __attribute__((ext_vector_type(8))) short  short8;   // 8 bf16 (4 VGPRs)
typedef __attribute__((ext_vector_type(4))) float  floatx4;  // MFMA acc

union Pack8 { short8 s; unsigned short h[8]; };

__device__ __forceinline__ float bf2f(unsigned short u) {
    union { unsigned int i; float f; } v; v.i = ((unsigned int)u) << 16; return v.f;
}
__device__ __forceinline__ unsigned short f2bf(float f) {
    union { float f; unsigned int i; } v; v.f = f;
    unsigned int b = v.i;
    b += 0x7FFFu + ((b >> 16) & 1u);   // RNE
    return (unsigned short)(b >> 16);
}
__device__ __forceinline__ float fast_tanh(float v) {
    float ex = __expf(v + v);
    return 1.f - 2.f / (ex + 1.f);
}

// ---------------------------------------------------------------------------
// Pack row-major fp32 [K][N] into bf16 B-fragment order:
//   Wp[ntile][kc][lane][8], lane = quad*16 + (n&15), j = k&7.
// ---------------------------------------------------------------------------
__global__ void pack_b_kernel(const float* __restrict__ W,
                              unsigned short* __restrict__ Wp, int K, int N) {
    int idx = blockIdx.x * blockDim.x + threadIdx.x;
    if (idx >= K * N) return;
    int k = idx / N, n = idx % N;
    int nt = n >> 4, kc = k >> 5, quad = (k >> 3) & 3, j = k & 7;
    int lane = quad * 16 + (n & 15);
    int KC = K >> 5;
    Wp[((size_t)(nt * KC + kc) * 64 + lane) * 8 + j] = f2bf(W[idx]);
}

// ---------------------------------------------------------------------------
// xproj: xp[tb][n] = sum_k xs[tb][k] * W1x[k][n], stored bf16.
// ---------------------------------------------------------------------------
__global__ __launch_bounds__(256) void xproj_kernel(
        const float* __restrict__ xs,
        const unsigned short* __restrict__ W1xp,
        unsigned short* __restrict__ xp) {
    const int tid  = threadIdx.x;
    const int lane = tid & 63;
    const int w    = tid >> 6;
    const int m    = lane & 15;
    const int q    = lane >> 4;
    const long row0 = (long)blockIdx.x * 16;

    short8 a[4];
#pragma unroll
    for (int kc = 0; kc < 4; ++kc) {
        const float* src = xs + (row0 + m) * DIN + kc * 32 + q * 8;
        Pack8 av;
#pragma unroll
        for (int j = 0; j < 8; ++j) av.h[j] = f2bf(src[j]);
        a[kc] = av.s;
    }

#pragma unroll
    for (int i = 0; i < 8; ++i) {
        const int nt = w * 8 + i;
        floatx4 acc = {0.f, 0.f, 0.f, 0.f};
#pragma unroll
        for (int kc = 0; kc < 4; ++kc) {
            short8 b = *(const short8*)(W1xp + ((size_t)(nt * 4 + kc) * 64 + lane) * 8);
            acc = __builtin_amdgcn_mfma_f32_16x16x32_bf16(a[kc], b, acc, 0, 0, 0);
        }
#pragma unroll
        for (int r = 0; r < 4; ++r)
            xp[(row0 + q * 4 + r) * DH + nt * 16 + m] = f2bf(acc[r]);
    }
}

// ---------------------------------------------------------------------------
// Recurrence: 16 blocks x 512 threads (8 waves, 2/SIMD). Block = 16 batch
// rows, all 512 h-cols. Wave w owns ntiles 4w..4w+3 (64 cols). W1h split:
//   kc 0..7        -> registers  (bfr: 128 VGPRs/lane; 256 KB/CU total)
//   kc 8..8+LKC-1  -> LDS        (Wl: LKC*32 KB, written once)
//   kc 8+LKC..15   -> streamed from L2 every step (2-kc groups, 2 buffers;
//                     CONSUME group g, THEN prefetch g+2 into the freed buf —
//                     g and g+2 share buffer (g&1), so order is correctness!)
// h double-buffered in LDS (row pad +8 -> 2-way-free b128 reads).
// Fully block-local: NO atomics, NO cross-block sync, 1 barrier/step.
// ---------------------------------------------------------------------------
template <int LKC>
__global__ __launch_bounds__(512, 2) void rnn_kernel(
        const unsigned short* __restrict__ xp,
        const unsigned short* __restrict__ W1hp,
        const float* __restrict__ b1p,
        const float* __restrict__ W2,
        const float* __restrict__ b2p,
        float* __restrict__ out) {
    extern __shared__ unsigned short smem[];
    // Hb: [2][16][520] at smem[0]; Wl: [LKC][32][64][8] at smem[16640]
    unsigned short* Hb = smem;
    unsigned short* Wl = smem + 2 * 16 * 520;
#define HB(b, r, c) Hb[(b) * 8320 + (r) * 520 + (c)]

    const int tid  = threadIdx.x;
    const int lane = tid & 63;
    const int w    = tid >> 6;      // 0..7
    const int m    = lane & 15;
    const int q    = lane >> 4;
    const int rg   = blockIdx.x;
    const float b1 = b1p[0];

    // ---- preload register-resident W1h (kc 0..7, wave's 4 ntiles) ----
    short8 bfr[8][4];
#pragma unroll
    for (int kc = 0; kc < 8; ++kc)
#pragma unroll
        for (int i = 0; i < 4; ++i)
            bfr[kc][i] = *(const short8*)(W1hp +
                ((size_t)((4 * w + i) * 16 + kc) * 64 + lane) * 8);

    // ---- fill LDS-resident W1h (kc 8..8+LKC-1), kc-major layout ----
    if (LKC > 0) {
        for (int c = tid; c < LKC * 2048; c += 512) {
            int j = c >> 11;          // kc-local
            int r = c & 2047;         // nt*64 + lane
            int nt = r >> 6, ln = r & 63;
            *(short8*)&Wl[(size_t)c * 8] =
                *(const short8*)(W1hp + ((size_t)(nt * 16 + 8 + j) * 64 + ln) * 8);
        }
    }

    // ---- h^1 = tanh(xp[0] + b1) -> Hb[0] ----
    for (int c = tid; c < 1024; c += 512) {
        int row = c >> 6, cc = c & 63;
        const unsigned short* src = xp + (size_t)(rg * 16 + row) * DH + cc * 8;
        Pack8 pk;
#pragma unroll
        for (int j = 0; j < 8; ++j) pk.h[j] = f2bf(fast_tanh(bf2f(src[j]) + b1));
        *(short8*)&HB(0, row, cc * 8) = pk.s;
    }
    __syncthreads();

    constexpr int KB = 8 + LKC;            // first streamed kc
    constexpr int NG = (8 - LKC + 1) / 2;  // 2-kc streamed groups

    int p = 0;
#pragma unroll 1
    for (int t = 1; t < T_STEPS; ++t) {
        // streamed-weight pipeline buffers (2 groups x 2 kc x 4 nt = 64 VGPRs)
        short8 sb[2][2][4];
        // preload groups 0 and 1 up front (L2-resident; latency covered by
        // the register/LDS-kc MFMA work below)
#pragma unroll
        for (int g = 0; g < 2 && g < NG; ++g)
#pragma unroll
            for (int c = 0; c < 2; ++c) {
                int kc = KB + 2 * g + c;
                if (kc < 16)
#pragma unroll
                    for (int i = 0; i < 4; ++i)
                        sb[g][c][i] = *(const short8*)(W1hp +
                            ((size_t)((4 * w + i) * 16 + kc) * 64 + lane) * 8);
            }

        // xp[t] prefetch for the epilogue (HBM latency hidden under MFMAs)
        unsigned short xv[4][4];
#pragma unroll
        for (int i = 0; i < 4; ++i)
#pragma unroll
            for (int r = 0; r < 4; ++r)
                xv[i][r] = xp[((size_t)t * BATCH + rg * 16 + q * 4 + r) * DH +
                              (4 * w + i) * 16 + m];

        floatx4 acc[4];
#pragma unroll
        for (int i = 0; i < 4; ++i) acc[i] = (floatx4){0.f, 0.f, 0.f, 0.f};

        // register-resident kcs
#pragma unroll
        for (int kc = 0; kc < 8; ++kc) {
            short8 a = *(const short8*)&HB(p, m, kc * 32 + q * 8);
#pragma unroll
            for (int i = 0; i < 4; ++i)
                acc[i] = __builtin_amdgcn_mfma_f32_16x16x32_bf16(a, bfr[kc][i], acc[i], 0, 0, 0);
        }

        // LDS-resident kcs
#pragma unroll
        for (int j = 0; j < LKC; ++j) {
            short8 a = *(const short8*)&HB(p, m, (8 + j) * 32 + q * 8);
#pragma unroll
            for (int i = 0; i < 4; ++i) {
                short8 b = *(const short8*)&Wl[((size_t)(j * 32 + 4 * w + i) * 64 + lane) * 8];
                acc[i] = __builtin_amdgcn_mfma_f32_16x16x32_bf16(a, b, acc[i], 0, 0, 0);
            }
        }

        // streamed kcs: CONSUME group g first, THEN prefetch group g+2 into
        // the buffer group g just freed (they alias: (g+2)&1 == g&1).
#pragma unroll
        for (int g = 0; g < NG; ++g) {
#pragma unroll
            for (int c = 0; c < 2; ++c) {
                int kc = KB + 2 * g + c;
                if (kc < 16) {
                    short8 a = *(const short8*)&HB(p, m, kc * 32 + q * 8);
#pragma unroll
                    for (int i = 0; i < 4; ++i)
                        acc[i] = __builtin_amdgcn_mfma_f32_16x16x32_bf16(a, sb[g & 1][c][i], acc[i], 0, 0, 0);
                }
            }
            if (g + 2 < NG) {
#pragma unroll
                for (int c = 0; c < 2; ++c) {
                    int kc = KB + 2 * (g + 2) + c;
                    if (kc < 16)
#pragma unroll
                        for (int i = 0; i < 4; ++i)
                            sb[g & 1][c][i] = *(const short8*)(W1hp +
                                ((size_t)((4 * w + i) * 16 + kc) * 64 + lane) * 8);
                }
            }
        }

        // epilogue: h^{t+1} = tanh(acc + xp + b1) -> other buffer
#pragma unroll
        for (int i = 0; i < 4; ++i)
#pragma unroll
            for (int r = 0; r < 4; ++r) {
                float v = acc[i][r] + bf2f(xv[i][r]) + b1;
                HB(1 - p, q * 4 + r, (4 * w + i) * 16 + m) = f2bf(fast_tanh(v));
            }
        __syncthreads();
        p ^= 1;
    }

    // ---- tail: out[:, 16w:16w+16) = h^512 @ W2 + b2 ----
    const float b2 = b2p[0];
    floatx4 acc = {0.f, 0.f, 0.f, 0.f};
#pragma unroll
    for (int kc = 0; kc < 16; ++kc) {
        short8 av = *(const short8*)&HB(p, m, kc * 32 + q * 8);
        Pack8 bv;
#pragma unroll
        for (int j = 0; j < 8; ++j)
            bv.h[j] = f2bf(W2[(size_t)(kc * 32 + q * 8 + j) * DOUT + w * 16 + m]);
        acc = __builtin_amdgcn_mfma_f32_16x16x32_bf16(av, bv.s, acc, 0, 0, 0);
    }
#pragma unroll
    for (int r = 0; r < 4; ++r)
        out[(size_t)(rg * 16 + q * 4 + r) * DOUT + w * 16 + m] = acc[r] + b2;
#undef HB
}

// ---------------------------------------------------------------------------
extern "C" void kernel_launch(void* const* d_in, const int* in_sizes, int n_in,
                              void* d_out, int out_size, void* d_ws, size_t ws_size,
                              hipStream_t stream) {
    const float* xs  = (const float*)d_in[0];
    const float* W1x = (const float*)d_in[1];
    const float* W1h = (const float*)d_in[2];
    const float* b1  = (const float*)d_in[3];
    const float* W2  = (const float*)d_in[4];
    const float* b2  = (const float*)d_in[5];
    float* out = (float*)d_out;

    // ws (bf16 elems): xp | W1h packed | W1x packed
    unsigned short* xp   = (unsigned short*)d_ws;
    unsigned short* w1hp = xp + (size_t)T_STEPS * BATCH * DH;      // 67,108,864
    unsigned short* w1xp = w1hp + (size_t)DH * DH;                 // +262,144

    pack_b_kernel<<<(DH * DH + 255) / 256, 256, 0, stream>>>(W1h, w1hp, DH, DH);
    pack_b_kernel<<<(DIN * DH + 255) / 256, 256, 0, stream>>>(W1x, w1xp, DIN, DH);
    xproj_kernel<<<(T_STEPS * BATCH) / 16, 256, 0, stream>>>(xs, w1xp, xp);

    // Big variant: Hb 33280 B + 3 kc of W1h in LDS (98304 B) = 131584 B dynamic
    // LDS (needs >64 KB opt-in). Fallback (opt-in unavailable): Hb only, stream
    // 8 kc from L2 each step. Decision is deterministic per machine -> graph-safe.
    constexpr size_t SMEM_BIG   = 2 * 16 * 520 * 2 + 3 * 32 * 64 * 8 * 2;  // 131584
    constexpr size_t SMEM_SMALL = 2 * 16 * 520 * 2;                        //  33280
    hipError_t e = hipFuncSetAttribute(
        reinterpret_cast<const void*>(&rnn_kernel<3>),
        hipFuncAttributeMaxDynamicSharedMemorySize, (int)SMEM_BIG);
    if (e == hipSuccess) {
        rnn_kernel<3><<<RGRP, 512, SMEM_BIG, stream>>>(xp, w1hp, b1, W2, b2, out);
    } else {
        rnn_kernel<0><<<RGRP, 512, SMEM_SMALL, stream>>>(xp, w1hp, b1, W2, b2, out);
    }
}